// Round 4
// baseline (975.835 us; speedup 1.0000x reference)
//
#include <hip/hip_runtime.h>
#include <math.h>

#define N_NODES 20000
#define N_EDGES 256000
#define F_IN 1024
#define C_DIM 1000
#define NEG_SLOPE 0.2f

#define MPAD 20224   // 158 * 128
#define KDIM 1024    // padded K for both layers
#define NW 2048      // fused weight rows: [0,1000)=Wl, [1024,2024)=Wr

typedef __attribute__((ext_vector_type(8))) short          bf16x8;
typedef __attribute__((ext_vector_type(8))) unsigned short u16x8;
typedef __attribute__((ext_vector_type(4))) float          f32x4;
typedef unsigned short us;

__device__ __forceinline__ us f2bf(float f) {
  unsigned u = __float_as_uint(f);
  return (us)((u + 0x7FFFu + ((u >> 16) & 1u)) >> 16);   // RNE
}
__device__ __forceinline__ float bf2f(us u) {
  return __uint_as_float(((unsigned)u) << 16);
}

__device__ __forceinline__ void gld16(void* lds, const void* g) {
  __builtin_amdgcn_global_load_lds(
      (const __attribute__((address_space(1))) unsigned int*)g,
      (__attribute__((address_space(3))) unsigned int*)lds, 16, 0, 0);
}

// ===================== CSR build (by dst) =====================
__global__ void count_k(const int* __restrict__ edst, int* __restrict__ counts) {
  int e = blockIdx.x * blockDim.x + threadIdx.x;
  if (e < N_EDGES) atomicAdd(&counts[edst[e]], 1);
}

// one block; thread t owns counts[t*20 .. t*20+19]
__global__ __launch_bounds__(1024)
void scan_k(const int* __restrict__ counts, int* __restrict__ row_ptr, int* __restrict__ cursor) {
  __shared__ int sm[1024];
  int t = threadIdx.x;
  int base = t * 20;
  int loc[20];
  int run = 0;
#pragma unroll
  for (int i = 0; i < 20; ++i) {
    int idx = base + i;
    int v = (idx < N_NODES) ? counts[idx] : 0;
    run += v;
    loc[i] = run;
  }
  sm[t] = run;
  __syncthreads();
  for (int off = 1; off < 1024; off <<= 1) {
    int v = (t >= off) ? sm[t - off] : 0;
    __syncthreads();
    sm[t] += v;
    __syncthreads();
  }
  int excl = (t > 0) ? sm[t - 1] : 0;
#pragma unroll
  for (int i = 0; i < 20; ++i) {
    int idx = base + i;
    if (idx < N_NODES) {
      int e = excl + ((i > 0) ? loc[i - 1] : 0);
      row_ptr[idx] = e;
      cursor[idx] = e;
    }
  }
  if (t == 0) row_ptr[N_NODES] = sm[1023];
}

__global__ void scatter_k(const int* __restrict__ esrc, const float* __restrict__ eattr,
                          const int* __restrict__ edst, int* __restrict__ cursor,
                          int2* __restrict__ spair) {
  int e = blockIdx.x * blockDim.x + threadIdx.x;
  if (e < N_EDGES) {
    int p = atomicAdd(&cursor[edst[e]], 1);
    spair[p] = make_int2(esrc[e], __float_as_int(eattr[e]));
  }
}

// ===================== fp32 -> padded bf16 (rows -> dstRows, cols -> 1024) =====
__global__ void cvt_pad_k(const float* __restrict__ src, us* __restrict__ dst,
                          int R, int C, int dstRows) {
  long total = (long)dstRows * 256;
  for (long i = (long)blockIdx.x * blockDim.x + threadIdx.x; i < total;
       i += (long)gridDim.x * blockDim.x) {
    int row = (int)(i >> 8);
    int c = ((int)(i & 255)) << 2;
    ushort4 o = make_ushort4(0, 0, 0, 0);
    if (row < R && c < C) {
      float4 v = *(const float4*)(src + (long)row * C + c);
      o.x = f2bf(v.x); o.y = f2bf(v.y); o.z = f2bf(v.z); o.w = f2bf(v.w);
    }
    *(ushort4*)(dst + ((long)row << 10) + c) = o;
  }
}

// ===================== fused bf16 MFMA GEMM =====================
// C[M,2048] = A[MPAD,1024] @ W2[2048,1024]^T. Tile 128(M)x256(N), BK=64,
// 8 waves (2M x 4N, wave tile 64x64), double-buffered LDS with XOR-swizzle:
// LDS rows are 128B (64 bf16); 16B-chunk slot = logical_chunk ^ (row&7) ->
// fragment ds_reads spread over all 32 banks (2-way only = free).
// global_load_lds writes linearly, so the swizzle is pre-applied on the
// GLOBAL source address (linear dest + inv-swz source + swz read).
__global__ __launch_bounds__(512)
void gemm_mfma_k(const us* __restrict__ Abf, const us* __restrict__ Wbf,
                 const float* __restrict__ bl, const float* __restrict__ br,
                 us* __restrict__ Cbf) {
  __shared__ us As[2][8192];    // [dbuf][128 rows][64 k]  = 16KB each
  __shared__ us Bs[2][16384];   // [dbuf][256 rows][64 k]  = 32KB each
  const int tid = threadIdx.x;
  const int lane = tid & 63;
  const int wv = tid >> 6;      // 0..7
  const int wr = wv >> 2;       // 0..1 (M half: 64 rows)
  const int wc = wv & 3;        // 0..3 (N quarter: 64 cols)

  // XCD mapping: 1264 wgs = 158 row-tiles x 8 col-tiles; each XCD (bid&7)
  // owns one 256-col tile -> its W-slice (512KB) is L2-resident.
  const long bm = (long)(blockIdx.x >> 3) * 128;
  const long bn = (long)(blockIdx.x & 7) * 256;

  f32x4 acc[4][4];
  const f32x4 z4 = {0.f, 0.f, 0.f, 0.f};
#pragma unroll
  for (int i = 0; i < 4; ++i)
#pragma unroll
    for (int j = 0; j < 4; ++j) acc[i][j] = z4;

  // staging sources, pre-inverse-swizzled: chunk c -> row=c>>3, slot=c&7,
  // logical kchunk = slot ^ (row&7)
  const us* srcA[2];
  const us* srcB[4];
#pragma unroll
  for (int r = 0; r < 2; ++r) {
    int c = tid + r * 512;
    int row = c >> 3;
    int kc = (c & 7) ^ (row & 7);
    srcA[r] = Abf + (bm + row) * KDIM + kc * 8;
  }
#pragma unroll
  for (int r = 0; r < 4; ++r) {
    int c = tid + r * 512;
    int row = c >> 3;
    int kc = (c & 7) ^ (row & 7);
    srcB[r] = Wbf + (bn + row) * KDIM + kc * 8;
  }

#define STAGE(buf, k0)                                          \
  {                                                             \
    _Pragma("unroll")                                           \
    for (int r = 0; r < 2; ++r)                                 \
      gld16(&As[buf][r * 4096 + wv * 512], srcA[r] + (k0));     \
    _Pragma("unroll")                                           \
    for (int r = 0; r < 4; ++r)                                 \
      gld16(&Bs[buf][r * 4096 + wv * 512], srcB[r] + (k0));     \
  }

  const int rA = lane & 15;
  const int g = lane >> 4;
  // swizzled k-offsets (us elements) for ks=0/1: chunk = (ks*4+g) ^ (rA&7)
  const int kb0 = ((g) ^ (rA & 7)) * 8;
  const int kb1 = ((4 + g) ^ (rA & 7)) * 8;
  const int arow = (wr * 64 + rA) * 64;   // element base, mi=0
  const int brow = (wc * 64 + rA) * 64;   // element base, ni=0

  STAGE(0, 0)

  for (int t = 0; t < 16; ++t) {
    __syncthreads();              // vmcnt(0)+lgkmcnt(0)+barrier: tile t visible
    if (t < 15) STAGE((t + 1) & 1, (t + 1) * 64)
    const us* Ar = As[t & 1];
    const us* Br = Bs[t & 1];
#pragma unroll
    for (int ks = 0; ks < 2; ++ks) {
      const int kb = ks ? kb1 : kb0;
      bf16x8 bv[4];
#pragma unroll
      for (int ni = 0; ni < 4; ++ni)
        bv[ni] = *(const bf16x8*)&Br[brow + ni * 1024 + kb];
      bf16x8 av[4];
#pragma unroll
      for (int mi = 0; mi < 4; ++mi)
        av[mi] = *(const bf16x8*)&Ar[arow + mi * 1024 + kb];
#pragma unroll
      for (int mi = 0; mi < 4; ++mi)
#pragma unroll
        for (int ni = 0; ni < 4; ++ni)
          acc[mi][ni] = __builtin_amdgcn_mfma_f32_16x16x32_bf16(av[mi], bv[ni], acc[mi][ni], 0, 0, 0);
    }
  }

  // epilogue
  int coln[4]; float bsv[4]; int cok[4];
#pragma unroll
  for (int ni = 0; ni < 4; ++ni) {
    coln[ni] = (int)bn + wc * 64 + ni * 16 + rA;
    int cm = coln[ni] & 1023;
    cok[ni] = (cm < C_DIM);
    bsv[ni] = cok[ni] ? ((coln[ni] < 1024) ? bl[cm] : br[cm]) : 0.f;
  }
#pragma unroll
  for (int mi = 0; mi < 4; ++mi) {
#pragma unroll
    for (int j = 0; j < 4; ++j) {
      int row = (int)bm + wr * 64 + mi * 16 + g * 4 + j;
      if (row < N_NODES) {
#pragma unroll
        for (int ni = 0; ni < 4; ++ni)
          if (cok[ni])
            Cbf[(long)row * NW + coln[ni]] = f2bf(acc[mi][ni][j] + bsv[ni]);
      }
    }
  }
#undef STAGE
}

// ===================== fused per-dst attention + aggregation =====================
// wave per dst via atomic work-queue (dynamic balance over degree variance);
// online softmax; edges unrolled x2. Deterministic: per-dst work is
// independent and internally order-fixed.
template <int ACT>
__global__ __launch_bounds__(256)
void edge_agg_k(const us* __restrict__ xlr, const int2* __restrict__ spair,
                const int* __restrict__ row_ptr, int* __restrict__ qctr,
                const float* __restrict__ We, const float* __restrict__ att,
                const float* __restrict__ bias, us* __restrict__ hout,
                float* __restrict__ fout) {
  const int lane = threadIdx.x & 63;
  const int q0 = lane, q1 = lane + 64;
  const bool ok1 = (q1 < 125);

  float attv[2][8], wev[2][8];
#pragma unroll
  for (int j = 0; j < 2; ++j) {
    int qq = lane + 64 * j;
    if (qq < 125) {
      float4 a0 = ((const float4*)att)[2 * qq], a1 = ((const float4*)att)[2 * qq + 1];
      float4 w0 = ((const float4*)We)[2 * qq],  w1 = ((const float4*)We)[2 * qq + 1];
      attv[j][0] = a0.x; attv[j][1] = a0.y; attv[j][2] = a0.z; attv[j][3] = a0.w;
      attv[j][4] = a1.x; attv[j][5] = a1.y; attv[j][6] = a1.z; attv[j][7] = a1.w;
      wev[j][0] = w0.x; wev[j][1] = w0.y; wev[j][2] = w0.z; wev[j][3] = w0.w;
      wev[j][4] = w1.x; wev[j][5] = w1.y; wev[j][6] = w1.z; wev[j][7] = w1.w;
    } else {
#pragma unroll
      for (int t = 0; t < 8; ++t) { attv[j][t] = 0.f; wev[j][t] = 0.f; }
    }
  }

  int d;
  if (lane == 0) d = atomicAdd(qctr, 1);
  d = __shfl(d, 0, 64);

  while (d < N_NODES) {
    const int beg = row_ptr[d];
    const int end = row_ptr[d + 1];

    float xrv[2][8];
    {
      const u16x8* xrp = (const u16x8*)(xlr + (long)d * NW + 1024);
#pragma unroll
      for (int j = 0; j < 2; ++j) {
        int qq = lane + 64 * j;
        if (qq < 125) {
          u16x8 h = xrp[qq];
#pragma unroll
          for (int t = 0; t < 8; ++t) xrv[j][t] = bf2f(h[t]);
        } else {
#pragma unroll
          for (int t = 0; t < 8; ++t) xrv[j][t] = 0.f;
        }
      }
    }

    float m = -INFINITY, denom = 0.f;
    float acc[2][8];
#pragma unroll
    for (int j = 0; j < 2; ++j)
#pragma unroll
      for (int t = 0; t < 8; ++t) acc[j][t] = 0.f;

#define EDGE_LOGIT(PAIR, VH0, VH1, PART)                                   \
    {                                                                      \
      const u16x8* xs = (const u16x8*)(xlr + (long)(PAIR).x * NW);         \
      float ea = __int_as_float((PAIR).y);                                 \
      VH0 = xs[q0];                                                        \
      if (ok1) VH1 = xs[q1];                                               \
      else { u16x8 zz = {0,0,0,0,0,0,0,0}; VH1 = zz; }                     \
      PART = 0.f;                                                          \
      _Pragma("unroll")                                                    \
      for (int t = 0; t < 8; ++t) {                                        \
        float tt = bf2f(VH0[t]) + xrv[0][t] + ea * wev[0][t];              \
        tt = (tt >= 0.f) ? tt : NEG_SLOPE * tt;                            \
        PART = fmaf(attv[0][t], tt, PART);                                 \
        float uu = bf2f(VH1[t]) + xrv[1][t] + ea * wev[1][t];              \
        uu = (uu >= 0.f) ? uu : NEG_SLOPE * uu;                            \
        PART = fmaf(attv[1][t], uu, PART);                                 \
      }                                                                    \
    }

#define ONLINE_UPDATE(PART, VH0, VH1)                                      \
    {                                                                      \
      if ((PART) > m) {                                                    \
        float sc = __expf(m - (PART));                                     \
        denom = denom * sc + 1.f;                                          \
        _Pragma("unroll")                                                  \
        for (int t = 0; t < 8; ++t) {                                      \
          acc[0][t] = fmaf(acc[0][t], sc, bf2f(VH0[t]));                   \
          acc[1][t] = fmaf(acc[1][t], sc, bf2f(VH1[t]));                   \
        }                                                                  \
        m = (PART);                                                        \
      } else {                                                             \
        float w = __expf((PART) - m);                                      \
        denom += w;                                                        \
        _Pragma("unroll")                                                  \
        for (int t = 0; t < 8; ++t) {                                      \
          acc[0][t] = fmaf(w, bf2f(VH0[t]), acc[0][t]);                    \
          acc[1][t] = fmaf(w, bf2f(VH1[t]), acc[1][t]);                    \
        }                                                                  \
      }                                                                    \
    }

    int i = beg;
    for (; i + 2 <= end; i += 2) {
      int2 p0 = spair[i], p1 = spair[i + 1];
      u16x8 a0, a1, b0, b1;
      float part0, part1;
      EDGE_LOGIT(p0, a0, a1, part0);
      EDGE_LOGIT(p1, b0, b1, part1);
#pragma unroll
      for (int off = 32; off > 0; off >>= 1) {
        part0 += __shfl_xor(part0, off, 64);
        part1 += __shfl_xor(part1, off, 64);
      }
      ONLINE_UPDATE(part0, a0, a1);
      ONLINE_UPDATE(part1, b0, b1);
    }
    if (i < end) {
      int2 p0 = spair[i];
      u16x8 a0, a1;
      float part0;
      EDGE_LOGIT(p0, a0, a1, part0);
#pragma unroll
      for (int off = 32; off > 0; off >>= 1) part0 += __shfl_xor(part0, off, 64);
      ONLINE_UPDATE(part0, a0, a1);
    }
#undef EDGE_LOGIT
#undef ONLINE_UPDATE

    float inv = 1.f / (denom + 1e-16f);
    if (ACT == 0) {
      us* orow = hout + ((long)d << 10);
#pragma unroll
      for (int j = 0; j < 2; ++j) {
        int qq = lane + 64 * j;
        u16x8 pk = {0, 0, 0, 0, 0, 0, 0, 0};
        if (qq < 125) {
          const float4 b0 = ((const float4*)bias)[2 * qq], b1 = ((const float4*)bias)[2 * qq + 1];
          const float bb[8] = {b0.x, b0.y, b0.z, b0.w, b1.x, b1.y, b1.z, b1.w};
#pragma unroll
          for (int t = 0; t < 8; ++t)
            pk[t] = f2bf(fmaxf(fmaf(acc[j][t], inv, bb[t]), 0.f));
        }
        ((u16x8*)orow)[qq] = pk;
      }
    } else {
#pragma unroll
      for (int j = 0; j < 2; ++j) {
        int qq = lane + 64 * j;
        if (qq < 125) {
          const float4 b0 = ((const float4*)bias)[2 * qq], b1 = ((const float4*)bias)[2 * qq + 1];
          const float bb[8] = {b0.x, b0.y, b0.z, b0.w, b1.x, b1.y, b1.z, b1.w};
          float o[8];
#pragma unroll
          for (int t = 0; t < 8; ++t)
            o[t] = 1.f / (1.f + __expf(-fmaf(acc[j][t], inv, bb[t])));
          float4* op = (float4*)(fout + (long)d * C_DIM + 8 * qq);
          op[0] = make_float4(o[0], o[1], o[2], o[3]);
          op[1] = make_float4(o[4], o[5], o[6], o[7]);
        }
      }
    }

    if (lane == 0) d = atomicAdd(qctr, 1);
    d = __shfl(d, 0, 64);
  }
}

// ===================== launch =====================
extern "C" void kernel_launch(void* const* d_in, const int* in_sizes, int n_in,
                              void* d_out, int out_size, void* d_ws, size_t ws_size,
                              hipStream_t stream) {
  const float* x     = (const float*)d_in[0];
  const int*   ei    = (const int*)d_in[1];
  const float* eattr = (const float*)d_in[2];
  const float* w1l   = (const float*)d_in[3];
  const float* b1l   = (const float*)d_in[4];
  const float* w1r   = (const float*)d_in[5];
  const float* b1r   = (const float*)d_in[6];
  const float* w1e   = (const float*)d_in[7];
  const float* att1  = (const float*)d_in[8];
  const float* bias1 = (const float*)d_in[9];
  const float* w2l   = (const float*)d_in[10];
  const float* b2l   = (const float*)d_in[11];
  const float* w2r   = (const float*)d_in[12];
  const float* b2r   = (const float*)d_in[13];
  const float* w2e   = (const float*)d_in[14];
  const float* att2  = (const float*)d_in[15];
  const float* bias2 = (const float*)d_in[16];
  float* out = (float*)d_out;

  // ws layout (bytes), total ~129.8 MB
  char* w = (char*)d_ws;
  us*  xlr  = (us*)w;                                  // 20000*2048*2 = 81,920,000
  us*  Abf  = (us*)(w + 81920000L);                    // 20224*1024*2 = 41,418,752
  us*  W2   = (us*)(w + 123338752L);                   // 2048*1024*2  =  4,194,304
  int2* spair = (int2*)(w + 127533056L);               // 256000*8     =  2,048,000
  int* row_ptr = (int*)(w + 129581056L);               // 20001*4
  int* cursor  = row_ptr + (N_NODES + 1);
  int* counts  = cursor + N_NODES;
  int* qctr    = counts + N_NODES;                     // 2 ints (layer1, layer2)

  const int* esrc = ei;
  const int* edst = ei + N_EDGES;

  // ---- CSR by dst + zero the work-queue counters ----
  hipMemsetAsync(counts, 0, (N_NODES + 2) * sizeof(int), stream);
  count_k<<<(N_EDGES + 255) / 256, 256, 0, stream>>>(edst, counts);
  scan_k<<<1, 1024, 0, stream>>>(counts, row_ptr, cursor);
  scatter_k<<<(N_EDGES + 255) / 256, 256, 0, stream>>>(esrc, eattr, edst, cursor, spair);

  // ---- layer 1 ----
  cvt_pad_k<<<4096, 256, 0, stream>>>(x, Abf, N_NODES, F_IN, MPAD);
  cvt_pad_k<<<1024, 256, 0, stream>>>(w1l, W2, C_DIM, F_IN, 1024);
  cvt_pad_k<<<1024, 256, 0, stream>>>(w1r, W2 + 1024 * 1024, C_DIM, F_IN, 1024);
  gemm_mfma_k<<<1264, 512, 0, stream>>>(Abf, W2, b1l, b1r, xlr);
  edge_agg_k<0><<<1024, 256, 0, stream>>>(xlr, spair, row_ptr, qctr, w1e, att1, bias1,
                                          Abf, nullptr);

  // ---- layer 2 (h is bf16 in Abf; pad rows/cols remain zero) ----
  cvt_pad_k<<<1024, 256, 0, stream>>>(w2l, W2, C_DIM, C_DIM, 1024);
  cvt_pad_k<<<1024, 256, 0, stream>>>(w2r, W2 + 1024 * 1024, C_DIM, C_DIM, 1024);
  gemm_mfma_k<<<1264, 512, 0, stream>>>(Abf, W2, b2l, b2r, xlr);
  edge_agg_k<1><<<1024, 256, 0, stream>>>(xlr, spair, row_ptr, qctr + 1, w2e, att2, bias2,
                                          nullptr, out);
}

// Round 5
// 557.765 us; speedup vs baseline: 1.7495x; 1.7495x over previous
//
#include <hip/hip_runtime.h>
#include <math.h>

#define N_NODES 20000
#define N_EDGES 256000
#define F_IN 1024
#define C_DIM 1000
#define NEG_SLOPE 0.2f

#define MPAD 20096   // 157 * 128
#define KDIM 1024    // padded K for both layers
#define NW 2048      // fused weight rows: [0,1000)=Wl, [1024,2024)=Wr

typedef __attribute__((ext_vector_type(8))) short          bf16x8;
typedef __attribute__((ext_vector_type(8))) unsigned short u16x8;
typedef __attribute__((ext_vector_type(4))) float          f32x4;
typedef unsigned short us;

__device__ __forceinline__ us f2bf(float f) {
  unsigned u = __float_as_uint(f);
  return (us)((u + 0x7FFFu + ((u >> 16) & 1u)) >> 16);   // RNE
}
__device__ __forceinline__ float bf2f(us u) {
  return __uint_as_float(((unsigned)u) << 16);
}

__device__ __forceinline__ void gld16(void* lds, const void* g) {
  __builtin_amdgcn_global_load_lds(
      (const __attribute__((address_space(1))) unsigned int*)g,
      (__attribute__((address_space(3))) unsigned int*)lds, 16, 0, 0);
}

// ===================== CSR build (by dst) =====================
__global__ void count_k(const int* __restrict__ edst, int* __restrict__ counts) {
  int e = blockIdx.x * blockDim.x + threadIdx.x;
  if (e < N_EDGES) atomicAdd(&counts[edst[e]], 1);
}

// one block; thread t owns counts[t*20 .. t*20+19]
__global__ __launch_bounds__(1024)
void scan_k(const int* __restrict__ counts, int* __restrict__ row_ptr, int* __restrict__ cursor) {
  __shared__ int sm[1024];
  int t = threadIdx.x;
  int base = t * 20;
  int loc[20];
  int run = 0;
#pragma unroll
  for (int i = 0; i < 20; ++i) {
    int idx = base + i;
    int v = (idx < N_NODES) ? counts[idx] : 0;
    run += v;
    loc[i] = run;
  }
  sm[t] = run;
  __syncthreads();
  for (int off = 1; off < 1024; off <<= 1) {
    int v = (t >= off) ? sm[t - off] : 0;
    __syncthreads();
    sm[t] += v;
    __syncthreads();
  }
  int excl = (t > 0) ? sm[t - 1] : 0;
#pragma unroll
  for (int i = 0; i < 20; ++i) {
    int idx = base + i;
    if (idx < N_NODES) {
      int e = excl + ((i > 0) ? loc[i - 1] : 0);
      row_ptr[idx] = e;
      cursor[idx] = e;
    }
  }
  if (t == 0) row_ptr[N_NODES] = sm[1023];
}

__global__ void scatter_k(const int* __restrict__ esrc, const float* __restrict__ eattr,
                          const int* __restrict__ edst, int* __restrict__ cursor,
                          int2* __restrict__ spair) {
  int e = blockIdx.x * blockDim.x + threadIdx.x;
  if (e < N_EDGES) {
    int p = atomicAdd(&cursor[edst[e]], 1);
    spair[p] = make_int2(esrc[e], __float_as_int(eattr[e]));
  }
}

// ===================== fp32 -> padded bf16 (rows -> dstRows, cols -> 1024) =====
__global__ void cvt_pad_k(const float* __restrict__ src, us* __restrict__ dst,
                          int R, int C, int dstRows) {
  long total = (long)dstRows * 256;
  for (long i = (long)blockIdx.x * blockDim.x + threadIdx.x; i < total;
       i += (long)gridDim.x * blockDim.x) {
    int row = (int)(i >> 8);
    int c = ((int)(i & 255)) << 2;
    ushort4 o = make_ushort4(0, 0, 0, 0);
    if (row < R && c < C) {
      float4 v = *(const float4*)(src + (long)row * C + c);
      o.x = f2bf(v.x); o.y = f2bf(v.y); o.z = f2bf(v.z); o.w = f2bf(v.w);
    }
    *(ushort4*)(dst + ((long)row << 10) + c) = o;
  }
}

// ===================== fused bf16 MFMA GEMM (round-3 proven: 123us, 685TF) =====
// C[M,2048] = A[MPAD,1024] @ W2[2048,1024]^T. 128x128 tile, BK=32, 4 waves,
// 2-phase double-buffered staging, XCD-chunked block swizzle (contiguous wg
// chunk per XCD -> ~5MB A-slice L2 locality).
__global__ __launch_bounds__(256)
void gemm_mfma_k(const us* __restrict__ Abf, const us* __restrict__ Wbf,
                 const float* __restrict__ bl, const float* __restrict__ br,
                 us* __restrict__ Cbf) {
  __shared__ us As0[4096], As1[4096], Bs0[4096], Bs1[4096];
  const int tid = threadIdx.x;
  const int lane = tid & 63;
  const int wv = tid >> 6;
  const int wr = wv >> 1, wc = wv & 1;

  const int nwg = gridDim.x;
  const int q = nwg >> 3;
  const int wg = (blockIdx.x & 7) * q + (blockIdx.x >> 3);
  const long bm = (long)(wg >> 4) * 128;   // 157 row-tiles
  const long bn = (long)(wg & 15) * 128;   // 16 col-tiles (N=2048)

  f32x4 acc[4][4];
  const f32x4 z4 = {0.f, 0.f, 0.f, 0.f};
#pragma unroll
  for (int i = 0; i < 4; ++i)
#pragma unroll
    for (int j = 0; j < 4; ++j) acc[i][j] = z4;

  const int i0 = tid, i1 = tid + 256;
  const us* gA0 = Abf + (bm + (i0 >> 2)) * KDIM + (i0 & 3) * 8;
  const us* gA1 = Abf + (bm + (i1 >> 2)) * KDIM + (i1 & 3) * 8;
  const us* gB0 = Wbf + (bn + (i0 >> 2)) * KDIM + (i0 & 3) * 8;
  const us* gB1 = Wbf + (bn + (i1 >> 2)) * KDIM + (i1 & 3) * 8;

  const int g = lane >> 4;
  const int rA = lane & 15;

  gld16(As0 + wv * 512, gA0);
  gld16(As0 + 2048 + wv * 512, gA1);
  gld16(Bs0 + wv * 512, gB0);
  gld16(Bs0 + 2048 + wv * 512, gB1);
  __syncthreads();

  for (int t = 0; t < 32; ++t) {
    if (t + 1 < 32) {
      int kn = (t + 1) << 5;
      us* dA = ((t + 1) & 1) ? As1 : As0;
      us* dB = ((t + 1) & 1) ? Bs1 : Bs0;
      gld16(dA + wv * 512, gA0 + kn);
      gld16(dA + 2048 + wv * 512, gA1 + kn);
      gld16(dB + wv * 512, gB0 + kn);
      gld16(dB + 2048 + wv * 512, gB1 + kn);
    }
    const us* Ar = (t & 1) ? As1 : As0;
    const us* Br = (t & 1) ? Bs1 : Bs0;
    bf16x8 av[4], bv[4];
#pragma unroll
    for (int mi = 0; mi < 4; ++mi)
      av[mi] = *(const bf16x8*)&Ar[(wr * 64 + mi * 16 + rA) * 32 + g * 8];
#pragma unroll
    for (int ni = 0; ni < 4; ++ni)
      bv[ni] = *(const bf16x8*)&Br[(wc * 64 + ni * 16 + rA) * 32 + g * 8];
#pragma unroll
    for (int mi = 0; mi < 4; ++mi)
#pragma unroll
      for (int ni = 0; ni < 4; ++ni)
        acc[mi][ni] = __builtin_amdgcn_mfma_f32_16x16x32_bf16(av[mi], bv[ni], acc[mi][ni], 0, 0, 0);
    __syncthreads();
  }

  int coln[4]; float biasv[4]; int cok[4];
#pragma unroll
  for (int ni = 0; ni < 4; ++ni) {
    coln[ni] = (int)bn + wc * 64 + ni * 16 + rA;
    int cm = coln[ni] & 1023;
    cok[ni] = (cm < C_DIM);
    biasv[ni] = cok[ni] ? ((coln[ni] < 1024) ? bl[cm] : br[cm]) : 0.f;
  }
#pragma unroll
  for (int mi = 0; mi < 4; ++mi) {
#pragma unroll
    for (int j = 0; j < 4; ++j) {
      int row = (int)bm + wr * 64 + mi * 16 + g * 4 + j;
      if (row < N_NODES) {
#pragma unroll
        for (int ni = 0; ni < 4; ++ni)
          if (cok[ni])
            Cbf[(long)row * NW + coln[ni]] = f2bf(acc[mi][ni][j] + biasv[ni]);
      }
    }
  }
}

// ===================== fused per-dst attention + aggregation =====================
// wave per dst (grid-stride static, NO work-queue: round-4's single-counter
// atomic queue serialized the phase, 296us vs 100us). Online softmax; edges
// unrolled x4 for memory-level parallelism (latency-bound gather chain).
template <int ACT>
__global__ __launch_bounds__(256)
void edge_agg_k(const us* __restrict__ xlr, const int2* __restrict__ spair,
                const int* __restrict__ row_ptr,
                const float* __restrict__ We, const float* __restrict__ att,
                const float* __restrict__ bias, us* __restrict__ hout,
                float* __restrict__ fout) {
  const int wave = threadIdx.x >> 6;
  const int lane = threadIdx.x & 63;
  const int q0 = lane, q1 = lane + 64;
  const bool ok1 = (q1 < 125);

  float attv[2][8], wev[2][8];
#pragma unroll
  for (int j = 0; j < 2; ++j) {
    int qq = lane + 64 * j;
    if (qq < 125) {
      float4 a0 = ((const float4*)att)[2 * qq], a1 = ((const float4*)att)[2 * qq + 1];
      float4 w0 = ((const float4*)We)[2 * qq],  w1 = ((const float4*)We)[2 * qq + 1];
      attv[j][0] = a0.x; attv[j][1] = a0.y; attv[j][2] = a0.z; attv[j][3] = a0.w;
      attv[j][4] = a1.x; attv[j][5] = a1.y; attv[j][6] = a1.z; attv[j][7] = a1.w;
      wev[j][0] = w0.x; wev[j][1] = w0.y; wev[j][2] = w0.z; wev[j][3] = w0.w;
      wev[j][4] = w1.x; wev[j][5] = w1.y; wev[j][6] = w1.z; wev[j][7] = w1.w;
    } else {
#pragma unroll
      for (int t = 0; t < 8; ++t) { attv[j][t] = 0.f; wev[j][t] = 0.f; }
    }
  }

  const int gw = (blockIdx.x << 2) | wave;
  const int stride = gridDim.x << 2;

  for (int d = gw; d < N_NODES; d += stride) {
    const int beg = row_ptr[d];
    const int end = row_ptr[d + 1];

    float xrv[2][8];
    {
      const u16x8* xrp = (const u16x8*)(xlr + (long)d * NW + 1024);
#pragma unroll
      for (int j = 0; j < 2; ++j) {
        int qq = lane + 64 * j;
        if (qq < 125) {
          u16x8 h = xrp[qq];
#pragma unroll
          for (int t = 0; t < 8; ++t) xrv[j][t] = bf2f(h[t]);
        } else {
#pragma unroll
          for (int t = 0; t < 8; ++t) xrv[j][t] = 0.f;
        }
      }
    }

    float m = -INFINITY, denom = 0.f;
    float acc[2][8];
#pragma unroll
    for (int j = 0; j < 2; ++j)
#pragma unroll
      for (int t = 0; t < 8; ++t) acc[j][t] = 0.f;

#define EDGE_LOGIT(PAIR, VH0, VH1, PART)                                   \
    {                                                                      \
      const u16x8* xs = (const u16x8*)(xlr + (long)(PAIR).x * NW);         \
      float ea = __int_as_float((PAIR).y);                                 \
      VH0 = xs[q0];                                                        \
      if (ok1) VH1 = xs[q1];                                               \
      else { u16x8 zz = {0,0,0,0,0,0,0,0}; VH1 = zz; }                     \
      PART = 0.f;                                                          \
      _Pragma("unroll")                                                    \
      for (int t = 0; t < 8; ++t) {                                        \
        float tt = bf2f(VH0[t]) + xrv[0][t] + ea * wev[0][t];              \
        tt = (tt >= 0.f) ? tt : NEG_SLOPE * tt;                            \
        PART = fmaf(attv[0][t], tt, PART);                                 \
        float uu = bf2f(VH1[t]) + xrv[1][t] + ea * wev[1][t];              \
        uu = (uu >= 0.f) ? uu : NEG_SLOPE * uu;                            \
        PART = fmaf(attv[1][t], uu, PART);                                 \
      }                                                                    \
    }

#define ONLINE_UPDATE(PART, VH0, VH1)                                      \
    {                                                                      \
      if ((PART) > m) {                                                    \
        float sc = __expf(m - (PART));                                     \
        denom = denom * sc + 1.f;                                          \
        _Pragma("unroll")                                                  \
        for (int t = 0; t < 8; ++t) {                                      \
          acc[0][t] = fmaf(acc[0][t], sc, bf2f(VH0[t]));                   \
          acc[1][t] = fmaf(acc[1][t], sc, bf2f(VH1[t]));                   \
        }                                                                  \
        m = (PART);                                                        \
      } else {                                                             \
        float w = __expf((PART) - m);                                      \
        denom += w;                                                        \
        _Pragma("unroll")                                                  \
        for (int t = 0; t < 8; ++t) {                                      \
          acc[0][t] = fmaf(w, bf2f(VH0[t]), acc[0][t]);                    \
          acc[1][t] = fmaf(w, bf2f(VH1[t]), acc[1][t]);                    \
        }                                                                  \
      }                                                                    \
    }

    int i = beg;
    // ---- x4-deep: 4 edges (8 row-gathers) in flight ----
    for (; i + 4 <= end; i += 4) {
      int2 p0 = spair[i], p1 = spair[i + 1], p2 = spair[i + 2], p3 = spair[i + 3];
      u16x8 a0, a1, b0, b1, c0, c1, e0, e1;
      float pt0, pt1, pt2, pt3;
      EDGE_LOGIT(p0, a0, a1, pt0);
      EDGE_LOGIT(p1, b0, b1, pt1);
      EDGE_LOGIT(p2, c0, c1, pt2);
      EDGE_LOGIT(p3, e0, e1, pt3);
#pragma unroll
      for (int off = 32; off > 0; off >>= 1) {
        pt0 += __shfl_xor(pt0, off, 64);
        pt1 += __shfl_xor(pt1, off, 64);
        pt2 += __shfl_xor(pt2, off, 64);
        pt3 += __shfl_xor(pt3, off, 64);
      }
      ONLINE_UPDATE(pt0, a0, a1);
      ONLINE_UPDATE(pt1, b0, b1);
      ONLINE_UPDATE(pt2, c0, c1);
      ONLINE_UPDATE(pt3, e0, e1);
    }
    for (; i + 2 <= end; i += 2) {
      int2 p0 = spair[i], p1 = spair[i + 1];
      u16x8 a0, a1, b0, b1;
      float pt0, pt1;
      EDGE_LOGIT(p0, a0, a1, pt0);
      EDGE_LOGIT(p1, b0, b1, pt1);
#pragma unroll
      for (int off = 32; off > 0; off >>= 1) {
        pt0 += __shfl_xor(pt0, off, 64);
        pt1 += __shfl_xor(pt1, off, 64);
      }
      ONLINE_UPDATE(pt0, a0, a1);
      ONLINE_UPDATE(pt1, b0, b1);
    }
    if (i < end) {
      int2 p0 = spair[i];
      u16x8 a0, a1;
      float pt0;
      EDGE_LOGIT(p0, a0, a1, pt0);
#pragma unroll
      for (int off = 32; off > 0; off >>= 1) pt0 += __shfl_xor(pt0, off, 64);
      ONLINE_UPDATE(pt0, a0, a1);
    }
#undef EDGE_LOGIT
#undef ONLINE_UPDATE

    float inv = 1.f / (denom + 1e-16f);
    if (ACT == 0) {
      us* orow = hout + ((long)d << 10);
#pragma unroll
      for (int j = 0; j < 2; ++j) {
        int qq = lane + 64 * j;
        u16x8 pk = {0, 0, 0, 0, 0, 0, 0, 0};
        if (qq < 125) {
          const float4 b0 = ((const float4*)bias)[2 * qq], b1 = ((const float4*)bias)[2 * qq + 1];
          const float bb[8] = {b0.x, b0.y, b0.z, b0.w, b1.x, b1.y, b1.z, b1.w};
#pragma unroll
          for (int t = 0; t < 8; ++t)
            pk[t] = f2bf(fmaxf(fmaf(acc[j][t], inv, bb[t]), 0.f));
        }
        ((u16x8*)orow)[qq] = pk;
      }
    } else {
#pragma unroll
      for (int j = 0; j < 2; ++j) {
        int qq = lane + 64 * j;
        if (qq < 125) {
          const float4 b0 = ((const float4*)bias)[2 * qq], b1 = ((const float4*)bias)[2 * qq + 1];
          const float bb[8] = {b0.x, b0.y, b0.z, b0.w, b1.x, b1.y, b1.z, b1.w};
          float o[8];
#pragma unroll
          for (int t = 0; t < 8; ++t)
            o[t] = 1.f / (1.f + __expf(-fmaf(acc[j][t], inv, bb[t])));
          float4* op = (float4*)(fout + (long)d * C_DIM + 8 * qq);
          op[0] = make_float4(o[0], o[1], o[2], o[3]);
          op[1] = make_float4(o[4], o[5], o[6], o[7]);
        }
      }
    }
  }
}

// ===================== launch =====================
extern "C" void kernel_launch(void* const* d_in, const int* in_sizes, int n_in,
                              void* d_out, int out_size, void* d_ws, size_t ws_size,
                              hipStream_t stream) {
  const float* x     = (const float*)d_in[0];
  const int*   ei    = (const int*)d_in[1];
  const float* eattr = (const float*)d_in[2];
  const float* w1l   = (const float*)d_in[3];
  const float* b1l   = (const float*)d_in[4];
  const float* w1r   = (const float*)d_in[5];
  const float* b1r   = (const float*)d_in[6];
  const float* w1e   = (const float*)d_in[7];
  const float* att1  = (const float*)d_in[8];
  const float* bias1 = (const float*)d_in[9];
  const float* w2l   = (const float*)d_in[10];
  const float* b2l   = (const float*)d_in[11];
  const float* w2r   = (const float*)d_in[12];
  const float* b2r   = (const float*)d_in[13];
  const float* w2e   = (const float*)d_in[14];
  const float* att2  = (const float*)d_in[15];
  const float* bias2 = (const float*)d_in[16];
  float* out = (float*)d_out;

  // ws layout (bytes), total ~130 MB
  char* w = (char*)d_ws;
  us*  xlr  = (us*)w;                                  // 20096*2048*2 = 82,313,216
  us*  Abf  = (us*)(w + 82313216L);                    // 20096*1024*2 = 41,156,608
  us*  W2   = (us*)(w + 123469824L);                   // 2048*1024*2  =  4,194,304
  int2* spair = (int2*)(w + 127664128L);               // 256000*8     =  2,048,000
  int* row_ptr = (int*)(w + 129712128L);               // 20001*4
  int* cursor  = row_ptr + (N_NODES + 1);
  int* counts  = cursor + N_NODES;

  const int* esrc = ei;
  const int* edst = ei + N_EDGES;

  // ---- CSR by dst, with sorted (src, eattr) pairs ----
  hipMemsetAsync(counts, 0, N_NODES * sizeof(int), stream);
  count_k<<<(N_EDGES + 255) / 256, 256, 0, stream>>>(edst, counts);
  scan_k<<<1, 1024, 0, stream>>>(counts, row_ptr, cursor);
  scatter_k<<<(N_EDGES + 255) / 256, 256, 0, stream>>>(esrc, eattr, edst, cursor, spair);

  // ---- layer 1 ----
  cvt_pad_k<<<4096, 256, 0, stream>>>(x, Abf, N_NODES, F_IN, MPAD);
  cvt_pad_k<<<1024, 256, 0, stream>>>(w1l, W2, C_DIM, F_IN, 1024);
  cvt_pad_k<<<1024, 256, 0, stream>>>(w1r, W2 + 1024 * 1024, C_DIM, F_IN, 1024);
  gemm_mfma_k<<<2512, 256, 0, stream>>>(Abf, W2, b1l, b1r, xlr);
  edge_agg_k<0><<<2048, 256, 0, stream>>>(xlr, spair, row_ptr, w1e, att1, bias1, Abf, nullptr);

  // ---- layer 2 (h is bf16 in Abf; pad rows 20000..20095 still zero from cvt) ----
  cvt_pad_k<<<1024, 256, 0, stream>>>(w2l, W2, C_DIM, C_DIM, 1024);
  cvt_pad_k<<<1024, 256, 0, stream>>>(w2r, W2 + 1024 * 1024, C_DIM, C_DIM, 1024);
  gemm_mfma_k<<<2512, 256, 0, stream>>>(Abf, W2, b2l, b2r, xlr);
  edge_agg_k<1><<<2048, 256, 0, stream>>>(xlr, spair, row_ptr, w2e, att2, bias2, nullptr, out);
}

// Round 6
// 524.864 us; speedup vs baseline: 1.8592x; 1.0627x over previous
//
#include <hip/hip_runtime.h>
#include <math.h>

#define N_NODES 20000
#define N_EDGES 256000
#define F_IN 1024
#define C_DIM 1000
#define NEG_SLOPE 0.2f

#define MPAD 20096   // 157 * 128
#define KDIM 1024    // padded K for both layers
#define NW 2048      // fused weight rows: [0,1000)=Wl, [1024,2024)=Wr

typedef __attribute__((ext_vector_type(8))) short          bf16x8;
typedef __attribute__((ext_vector_type(8))) unsigned short u16x8;
typedef __attribute__((ext_vector_type(4))) float          f32x4;
typedef unsigned short us;

__device__ __forceinline__ us f2bf(float f) {
  unsigned u = __float_as_uint(f);
  return (us)((u + 0x7FFFu + ((u >> 16) & 1u)) >> 16);   // RNE
}
__device__ __forceinline__ float bf2f(us u) {
  return __uint_as_float(((unsigned)u) << 16);
}

__device__ __forceinline__ void gld16(void* lds, const void* g) {
  __builtin_amdgcn_global_load_lds(
      (const __attribute__((address_space(1))) unsigned int*)g,
      (__attribute__((address_space(3))) unsigned int*)lds, 16, 0, 0);
}

// ===================== CSR build (by dst) =====================
__global__ void count_k(const int* __restrict__ edst, int* __restrict__ counts) {
  int e = blockIdx.x * blockDim.x + threadIdx.x;
  if (e < N_EDGES) atomicAdd(&counts[edst[e]], 1);
}

// one block; thread t owns counts[t*20 .. t*20+19]
__global__ __launch_bounds__(1024)
void scan_k(const int* __restrict__ counts, int* __restrict__ row_ptr, int* __restrict__ cursor) {
  __shared__ int sm[1024];
  int t = threadIdx.x;
  int base = t * 20;
  int loc[20];
  int run = 0;
#pragma unroll
  for (int i = 0; i < 20; ++i) {
    int idx = base + i;
    int v = (idx < N_NODES) ? counts[idx] : 0;
    run += v;
    loc[i] = run;
  }
  sm[t] = run;
  __syncthreads();
  for (int off = 1; off < 1024; off <<= 1) {
    int v = (t >= off) ? sm[t - off] : 0;
    __syncthreads();
    sm[t] += v;
    __syncthreads();
  }
  int excl = (t > 0) ? sm[t - 1] : 0;
#pragma unroll
  for (int i = 0; i < 20; ++i) {
    int idx = base + i;
    if (idx < N_NODES) {
      int e = excl + ((i > 0) ? loc[i - 1] : 0);
      row_ptr[idx] = e;
      cursor[idx] = e;
    }
  }
  if (t == 0) row_ptr[N_NODES] = sm[1023];
}

__global__ void scatter_k(const int* __restrict__ esrc, const float* __restrict__ eattr,
                          const int* __restrict__ edst, int* __restrict__ cursor,
                          int2* __restrict__ spair) {
  int e = blockIdx.x * blockDim.x + threadIdx.x;
  if (e < N_EDGES) {
    int p = atomicAdd(&cursor[edst[e]], 1);
    spair[p] = make_int2(esrc[e], __float_as_int(eattr[e]));
  }
}

// ===================== fp32 -> padded bf16 (rows -> dstRows, cols -> 1024) =====
__global__ void cvt_pad_k(const float* __restrict__ src, us* __restrict__ dst,
                          int R, int C, int dstRows) {
  long total = (long)dstRows * 256;
  for (long i = (long)blockIdx.x * blockDim.x + threadIdx.x; i < total;
       i += (long)gridDim.x * blockDim.x) {
    int row = (int)(i >> 8);
    int c = ((int)(i & 255)) << 2;
    ushort4 o = make_ushort4(0, 0, 0, 0);
    if (row < R && c < C) {
      float4 v = *(const float4*)(src + (long)row * C + c);
      o.x = f2bf(v.x); o.y = f2bf(v.y); o.z = f2bf(v.z); o.w = f2bf(v.w);
    }
    *(ushort4*)(dst + ((long)row << 10) + c) = o;
  }
}

// ===================== fused bf16 MFMA GEMM (round-3 proven: 123us, 685TF) =====
// C[M,2048] = A[MPAD,1024] @ W2[2048,1024]^T. 128x128 tile, BK=32, 4 waves,
// 2-phase double-buffered staging, XCD-chunked block swizzle (contiguous wg
// chunk per XCD -> ~5MB A-slice L2 locality).
__global__ __launch_bounds__(256)
void gemm_mfma_k(const us* __restrict__ Abf, const us* __restrict__ Wbf,
                 const float* __restrict__ bl, const float* __restrict__ br,
                 us* __restrict__ Cbf) {
  __shared__ us As0[4096], As1[4096], Bs0[4096], Bs1[4096];
  const int tid = threadIdx.x;
  const int lane = tid & 63;
  const int wv = tid >> 6;
  const int wr = wv >> 1, wc = wv & 1;

  const int nwg = gridDim.x;
  const int q = nwg >> 3;
  const int wg = (blockIdx.x & 7) * q + (blockIdx.x >> 3);
  const long bm = (long)(wg >> 4) * 128;   // 157 row-tiles
  const long bn = (long)(wg & 15) * 128;   // 16 col-tiles (N=2048)

  f32x4 acc[4][4];
  const f32x4 z4 = {0.f, 0.f, 0.f, 0.f};
#pragma unroll
  for (int i = 0; i < 4; ++i)
#pragma unroll
    for (int j = 0; j < 4; ++j) acc[i][j] = z4;

  const int i0 = tid, i1 = tid + 256;
  const us* gA0 = Abf + (bm + (i0 >> 2)) * KDIM + (i0 & 3) * 8;
  const us* gA1 = Abf + (bm + (i1 >> 2)) * KDIM + (i1 & 3) * 8;
  const us* gB0 = Wbf + (bn + (i0 >> 2)) * KDIM + (i0 & 3) * 8;
  const us* gB1 = Wbf + (bn + (i1 >> 2)) * KDIM + (i1 & 3) * 8;

  const int g = lane >> 4;
  const int rA = lane & 15;

  gld16(As0 + wv * 512, gA0);
  gld16(As0 + 2048 + wv * 512, gA1);
  gld16(Bs0 + wv * 512, gB0);
  gld16(Bs0 + 2048 + wv * 512, gB1);
  __syncthreads();

  for (int t = 0; t < 32; ++t) {
    if (t + 1 < 32) {
      int kn = (t + 1) << 5;
      us* dA = ((t + 1) & 1) ? As1 : As0;
      us* dB = ((t + 1) & 1) ? Bs1 : Bs0;
      gld16(dA + wv * 512, gA0 + kn);
      gld16(dA + 2048 + wv * 512, gA1 + kn);
      gld16(dB + wv * 512, gB0 + kn);
      gld16(dB + 2048 + wv * 512, gB1 + kn);
    }
    const us* Ar = (t & 1) ? As1 : As0;
    const us* Br = (t & 1) ? Bs1 : Bs0;
    bf16x8 av[4], bv[4];
#pragma unroll
    for (int mi = 0; mi < 4; ++mi)
      av[mi] = *(const bf16x8*)&Ar[(wr * 64 + mi * 16 + rA) * 32 + g * 8];
#pragma unroll
    for (int ni = 0; ni < 4; ++ni)
      bv[ni] = *(const bf16x8*)&Br[(wc * 64 + ni * 16 + rA) * 32 + g * 8];
#pragma unroll
    for (int mi = 0; mi < 4; ++mi)
#pragma unroll
      for (int ni = 0; ni < 4; ++ni)
        acc[mi][ni] = __builtin_amdgcn_mfma_f32_16x16x32_bf16(av[mi], bv[ni], acc[mi][ni], 0, 0, 0);
    __syncthreads();
  }

  int coln[4]; float biasv[4]; int cok[4];
#pragma unroll
  for (int ni = 0; ni < 4; ++ni) {
    coln[ni] = (int)bn + wc * 64 + ni * 16 + rA;
    int cm = coln[ni] & 1023;
    cok[ni] = (cm < C_DIM);
    biasv[ni] = cok[ni] ? ((coln[ni] < 1024) ? bl[cm] : br[cm]) : 0.f;
  }
#pragma unroll
  for (int mi = 0; mi < 4; ++mi) {
#pragma unroll
    for (int j = 0; j < 4; ++j) {
      int row = (int)bm + wr * 64 + mi * 16 + g * 4 + j;
      if (row < N_NODES) {
#pragma unroll
        for (int ni = 0; ni < 4; ++ni)
          if (cok[ni])
            Cbf[(long)row * NW + coln[ni]] = f2bf(acc[mi][ni][j] + biasv[ni]);
      }
    }
  }
}

// ===================== fused per-dst attention + aggregation =====================
// ONE dst per wave, grid = N_NODES/4 blocks: hardware block dispatch provides
// dynamic load balancing (no atomics - round-4's queue serialized; no
// grid-stride - round-3/5's static multi-dst assignment left a tail).
// Online softmax; edges unrolled x2 (x4 regressed: VGPR 92, occupancy 17%).
template <int ACT>
__global__ __launch_bounds__(256)
void edge_agg_k(const us* __restrict__ xlr, const int2* __restrict__ spair,
                const int* __restrict__ row_ptr,
                const float* __restrict__ We, const float* __restrict__ att,
                const float* __restrict__ bias, us* __restrict__ hout,
                float* __restrict__ fout) {
  const int wave = threadIdx.x >> 6;
  const int lane = threadIdx.x & 63;
  const int q0 = lane, q1 = lane + 64;
  const bool ok1 = (q1 < 125);

  const int d = (blockIdx.x << 2) | wave;
  if (d >= N_NODES) return;

  float attv[2][8], wev[2][8];
#pragma unroll
  for (int j = 0; j < 2; ++j) {
    int qq = lane + 64 * j;
    if (qq < 125) {
      float4 a0 = ((const float4*)att)[2 * qq], a1 = ((const float4*)att)[2 * qq + 1];
      float4 w0 = ((const float4*)We)[2 * qq],  w1 = ((const float4*)We)[2 * qq + 1];
      attv[j][0] = a0.x; attv[j][1] = a0.y; attv[j][2] = a0.z; attv[j][3] = a0.w;
      attv[j][4] = a1.x; attv[j][5] = a1.y; attv[j][6] = a1.z; attv[j][7] = a1.w;
      wev[j][0] = w0.x; wev[j][1] = w0.y; wev[j][2] = w0.z; wev[j][3] = w0.w;
      wev[j][4] = w1.x; wev[j][5] = w1.y; wev[j][6] = w1.z; wev[j][7] = w1.w;
    } else {
#pragma unroll
      for (int t = 0; t < 8; ++t) { attv[j][t] = 0.f; wev[j][t] = 0.f; }
    }
  }

  const int beg = row_ptr[d];
  const int end = row_ptr[d + 1];

  float xrv[2][8];
  {
    const u16x8* xrp = (const u16x8*)(xlr + (long)d * NW + 1024);
#pragma unroll
    for (int j = 0; j < 2; ++j) {
      int qq = lane + 64 * j;
      if (qq < 125) {
        u16x8 h = xrp[qq];
#pragma unroll
        for (int t = 0; t < 8; ++t) xrv[j][t] = bf2f(h[t]);
      } else {
#pragma unroll
        for (int t = 0; t < 8; ++t) xrv[j][t] = 0.f;
      }
    }
  }

  float m = -INFINITY, denom = 0.f;
  float acc[2][8];
#pragma unroll
  for (int j = 0; j < 2; ++j)
#pragma unroll
    for (int t = 0; t < 8; ++t) acc[j][t] = 0.f;

#define EDGE_LOGIT(PAIR, VH0, VH1, PART)                                   \
  {                                                                        \
    const u16x8* xs = (const u16x8*)(xlr + (long)(PAIR).x * NW);           \
    float ea = __int_as_float((PAIR).y);                                   \
    VH0 = xs[q0];                                                          \
    if (ok1) VH1 = xs[q1];                                                 \
    else { u16x8 zz = {0,0,0,0,0,0,0,0}; VH1 = zz; }                       \
    PART = 0.f;                                                            \
    _Pragma("unroll")                                                      \
    for (int t = 0; t < 8; ++t) {                                          \
      float tt = bf2f(VH0[t]) + xrv[0][t] + ea * wev[0][t];                \
      tt = (tt >= 0.f) ? tt : NEG_SLOPE * tt;                              \
      PART = fmaf(attv[0][t], tt, PART);                                   \
      float uu = bf2f(VH1[t]) + xrv[1][t] + ea * wev[1][t];                \
      uu = (uu >= 0.f) ? uu : NEG_SLOPE * uu;                              \
      PART = fmaf(attv[1][t], uu, PART);                                   \
    }                                                                      \
  }

#define ONLINE_UPDATE(PART, VH0, VH1)                                      \
  {                                                                        \
    if ((PART) > m) {                                                      \
      float sc = __expf(m - (PART));                                       \
      denom = denom * sc + 1.f;                                            \
      _Pragma("unroll")                                                    \
      for (int t = 0; t < 8; ++t) {                                        \
        acc[0][t] = fmaf(acc[0][t], sc, bf2f(VH0[t]));                     \
        acc[1][t] = fmaf(acc[1][t], sc, bf2f(VH1[t]));                     \
      }                                                                    \
      m = (PART);                                                          \
    } else {                                                               \
      float w = __expf((PART) - m);                                        \
      denom += w;                                                          \
      _Pragma("unroll")                                                    \
      for (int t = 0; t < 8; ++t) {                                        \
        acc[0][t] = fmaf(w, bf2f(VH0[t]), acc[0][t]);                      \
        acc[1][t] = fmaf(w, bf2f(VH1[t]), acc[1][t]);                      \
      }                                                                    \
    }                                                                      \
  }

  int i = beg;
  for (; i + 2 <= end; i += 2) {
    int2 p0 = spair[i], p1 = spair[i + 1];
    u16x8 a0, a1, b0, b1;
    float pt0, pt1;
    EDGE_LOGIT(p0, a0, a1, pt0);
    EDGE_LOGIT(p1, b0, b1, pt1);
#pragma unroll
    for (int off = 32; off > 0; off >>= 1) {
      pt0 += __shfl_xor(pt0, off, 64);
      pt1 += __shfl_xor(pt1, off, 64);
    }
    ONLINE_UPDATE(pt0, a0, a1);
    ONLINE_UPDATE(pt1, b0, b1);
  }
  if (i < end) {
    int2 p0 = spair[i];
    u16x8 a0, a1;
    float pt0;
    EDGE_LOGIT(p0, a0, a1, pt0);
#pragma unroll
    for (int off = 32; off > 0; off >>= 1) pt0 += __shfl_xor(pt0, off, 64);
    ONLINE_UPDATE(pt0, a0, a1);
  }
#undef EDGE_LOGIT
#undef ONLINE_UPDATE

  float inv = 1.f / (denom + 1e-16f);
  if (ACT == 0) {
    us* orow = hout + ((long)d << 10);
#pragma unroll
    for (int j = 0; j < 2; ++j) {
      int qq = lane + 64 * j;
      u16x8 pk = {0, 0, 0, 0, 0, 0, 0, 0};
      if (qq < 125) {
        const float4 b0 = ((const float4*)bias)[2 * qq], b1 = ((const float4*)bias)[2 * qq + 1];
        const float bb[8] = {b0.x, b0.y, b0.z, b0.w, b1.x, b1.y, b1.z, b1.w};
#pragma unroll
        for (int t = 0; t < 8; ++t)
          pk[t] = f2bf(fmaxf(fmaf(acc[j][t], inv, bb[t]), 0.f));
      }
      ((u16x8*)orow)[qq] = pk;
    }
  } else {
#pragma unroll
    for (int j = 0; j < 2; ++j) {
      int qq = lane + 64 * j;
      if (qq < 125) {
        const float4 b0 = ((const float4*)bias)[2 * qq], b1 = ((const float4*)bias)[2 * qq + 1];
        const float bb[8] = {b0.x, b0.y, b0.z, b0.w, b1.x, b1.y, b1.z, b1.w};
        float o[8];
#pragma unroll
        for (int t = 0; t < 8; ++t)
          o[t] = 1.f / (1.f + __expf(-fmaf(acc[j][t], inv, bb[t])));
        float4* op = (float4*)(fout + (long)d * C_DIM + 8 * qq);
        op[0] = make_float4(o[0], o[1], o[2], o[3]);
        op[1] = make_float4(o[4], o[5], o[6], o[7]);
      }
    }
  }
}

// ===================== launch =====================
extern "C" void kernel_launch(void* const* d_in, const int* in_sizes, int n_in,
                              void* d_out, int out_size, void* d_ws, size_t ws_size,
                              hipStream_t stream) {
  const float* x     = (const float*)d_in[0];
  const int*   ei    = (const int*)d_in[1];
  const float* eattr = (const float*)d_in[2];
  const float* w1l   = (const float*)d_in[3];
  const float* b1l   = (const float*)d_in[4];
  const float* w1r   = (const float*)d_in[5];
  const float* b1r   = (const float*)d_in[6];
  const float* w1e   = (const float*)d_in[7];
  const float* att1  = (const float*)d_in[8];
  const float* bias1 = (const float*)d_in[9];
  const float* w2l   = (const float*)d_in[10];
  const float* b2l   = (const float*)d_in[11];
  const float* w2r   = (const float*)d_in[12];
  const float* b2r   = (const float*)d_in[13];
  const float* w2e   = (const float*)d_in[14];
  const float* att2  = (const float*)d_in[15];
  const float* bias2 = (const float*)d_in[16];
  float* out = (float*)d_out;

  // ws layout (bytes), total ~134 MB (round-1 proved >=161MB available)
  char* w = (char*)d_ws;
  us*  xlr  = (us*)w;                                  // 20096*2048*2 = 82,313,216
  us*  Abf  = (us*)(w + 82313216L);                    // 20096*1024*2 = 41,156,608
  us*  W21  = (us*)(w + 123469824L);                   // 2048*1024*2  =  4,194,304
  us*  W22  = (us*)(w + 127664128L);                   // 2048*1024*2  =  4,194,304
  int2* spair = (int2*)(w + 131858432L);               // 256000*8     =  2,048,000
  int* row_ptr = (int*)(w + 133906432L);               // 20001*4
  int* cursor  = row_ptr + (N_NODES + 1);
  int* counts  = cursor + N_NODES;

  const int* esrc = ei;
  const int* edst = ei + N_EDGES;

  // ---- CSR by dst, with sorted (src, eattr) pairs ----
  hipMemsetAsync(counts, 0, N_NODES * sizeof(int), stream);
  count_k<<<(N_EDGES + 255) / 256, 256, 0, stream>>>(edst, counts);
  scan_k<<<1, 1024, 0, stream>>>(counts, row_ptr, cursor);
  scatter_k<<<(N_EDGES + 255) / 256, 256, 0, stream>>>(esrc, eattr, edst, cursor, spair);

  // ---- all weight conversions up-front ----
  cvt_pad_k<<<1024, 256, 0, stream>>>(w1l, W21, C_DIM, F_IN, 1024);
  cvt_pad_k<<<1024, 256, 0, stream>>>(w1r, W21 + 1024 * 1024, C_DIM, F_IN, 1024);
  cvt_pad_k<<<1024, 256, 0, stream>>>(w2l, W22, C_DIM, C_DIM, 1024);
  cvt_pad_k<<<1024, 256, 0, stream>>>(w2r, W22 + 1024 * 1024, C_DIM, C_DIM, 1024);

  // ---- layer 1 ----
  cvt_pad_k<<<4096, 256, 0, stream>>>(x, Abf, N_NODES, F_IN, MPAD);
  gemm_mfma_k<<<2512, 256, 0, stream>>>(Abf, W21, b1l, b1r, xlr);
  edge_agg_k<0><<<N_NODES / 4, 256, 0, stream>>>(xlr, spair, row_ptr, w1e, att1, bias1,
                                                 Abf, nullptr);

  // ---- layer 2 (h is bf16 in Abf; pad rows 20000..20095 still zero from cvt) ----
  gemm_mfma_k<<<2512, 256, 0, stream>>>(Abf, W22, b2l, b2r, xlr);
  edge_agg_k<1><<<N_NODES / 4, 256, 0, stream>>>(xlr, spair, row_ptr, w2e, att2, bias2,
                                                 nullptr, out);
}